// Round 1
// baseline (821.707 us; speedup 1.0000x reference)
//
#include <hip/hip_runtime.h>

#define NPTS   300000
#define NPAIRS 100000
#define KOFF   27
#define CIN    32
#define COUT   64
#define NGROUP 8
#define EPSV   1e-5f
#define SLOPE  0.01f

#define PAIRS_PER_BLOCK 256
#define BLOCKS_PER_K ((NPAIRS + PAIRS_PER_BLOCK - 1) / PAIRS_PER_BLOCK)  // 391

// ---------------------------------------------------------------- zero
__global__ __launch_bounds__(256) void zero_kernel(float4* __restrict__ out4, int n4,
                                                   float* __restrict__ stats) {
    int i = blockIdx.x * blockDim.x + threadIdx.x;
    if (i < n4) out4[i] = make_float4(0.f, 0.f, 0.f, 0.f);
    if (blockIdx.x == 0 && threadIdx.x < 16) stats[threadIdx.x] = 0.f;
}

// ---------------------------------------------------------------- conv (gather-matmul-scatter)
// One wave processes a stream of pairs for a single kernel offset k.
// lane = output channel c. Weight column W[k][:, c] lives in 32 VGPRs.
// Pair row indices are wave-uniform -> feats row loads should scalarize.
__global__ __launch_bounds__(256) void conv_kernel(
    const float* __restrict__ feats, const float* __restrict__ weight,
    const int* __restrict__ in_idx, const int* __restrict__ out_idx,
    float* __restrict__ out)
{
    const int lane = threadIdx.x & 63;
    const int wave = threadIdx.x >> 6;
    const int k     = blockIdx.x / BLOCKS_PER_K;
    const int pair0 = (blockIdx.x % BLOCKS_PER_K) * PAIRS_PER_BLOCK;

    // per-lane weight column, loaded once per block (coalesced across lanes)
    float w[CIN];
    const float* wk = weight + k * (CIN * COUT) + lane;
#pragma unroll
    for (int i = 0; i < CIN; ++i) w[i] = wk[i * COUT];

    const int per_wave = PAIRS_PER_BLOCK / 4;         // 64 pairs per wave
    int p    = pair0 + wave * per_wave;
    int pend = p + per_wave;
    if (pend > NPAIRS) pend = NPAIRS;

    const int* ii = in_idx  + k * NPAIRS;
    const int* oi = out_idx + k * NPAIRS;

    for (; p < pend; ++p) {
        int rin  = __builtin_amdgcn_readfirstlane(ii[p]);   // wave-uniform
        int rout = __builtin_amdgcn_readfirstlane(oi[p]);
        const float* frow = feats + (size_t)rin * CIN;
        float acc = 0.f;
#pragma unroll
        for (int i = 0; i < CIN; ++i)
            acc = fmaf(frow[i], w[i], acc);                 // frow[i] uniform -> SGPR operand
        atomicAdd(out + (size_t)rout * COUT + lane, acc);   // coalesced 64-lane atomic
    }
}

// ---------------------------------------------------------------- group stats (sum, sumsq)
__global__ __launch_bounds__(256) void stats_kernel(const float* __restrict__ out,
                                                    float* __restrict__ stats) {
    const int c = threadIdx.x & 63;                     // channel
    const int wave_in_grid = blockIdx.x * 4 + (threadIdx.x >> 6);
    const int nwaves = gridDim.x * 4;
    float s = 0.f, ss = 0.f;
    for (int r = wave_in_grid; r < NPTS; r += nwaves) {
        float v = out[(size_t)r * COUT + c];
        s += v; ss += v * v;
    }
    // reduce the 8 lanes of each channel group (group = c >> 3)
#pragma unroll
    for (int m = 1; m < 8; m <<= 1) {
        s  += __shfl_xor(s,  m, 64);
        ss += __shfl_xor(ss, m, 64);
    }
    if ((c & 7) == 0) {
        int g = c >> 3;
        atomicAdd(stats + g,     s);
        atomicAdd(stats + 8 + g, ss);
    }
}

// ---------------------------------------------------------------- normalize + affine + leaky relu
__global__ __launch_bounds__(256) void norm_kernel(float4* __restrict__ out4, int n4,
                                                   const float* __restrict__ stats,
                                                   const float* __restrict__ gamma,
                                                   const float* __restrict__ beta) {
    int i = blockIdx.x * blockDim.x + threadIdx.x;
    if (i >= n4) return;
    int c0 = (i & 15) * 4;              // first channel of this float4; stays in one group
    int g  = c0 >> 3;
    const float cnt = (float)NPTS * (COUT / NGROUP);
    float mean = stats[g] / cnt;
    float var  = stats[8 + g] / cnt - mean * mean;
    float inv  = rsqrtf(var + EPSV);
    float4 v  = out4[i];
    float4 ga = *(const float4*)(gamma + c0);
    float4 be = *(const float4*)(beta  + c0);
    float x;
    x = (v.x - mean) * inv * ga.x + be.x; v.x = x >= 0.f ? x : SLOPE * x;
    x = (v.y - mean) * inv * ga.y + be.y; v.y = x >= 0.f ? x : SLOPE * x;
    x = (v.z - mean) * inv * ga.z + be.z; v.z = x >= 0.f ? x : SLOPE * x;
    x = (v.w - mean) * inv * ga.w + be.w; v.w = x >= 0.f ? x : SLOPE * x;
    out4[i] = v;
}

// ---------------------------------------------------------------- launch
extern "C" void kernel_launch(void* const* d_in, const int* in_sizes, int n_in,
                              void* d_out, int out_size, void* d_ws, size_t ws_size,
                              hipStream_t stream) {
    const float* feats  = (const float*)d_in[0];
    const float* weight = (const float*)d_in[1];
    const float* gamma  = (const float*)d_in[2];
    const float* beta   = (const float*)d_in[3];
    const int*   in_idx = (const int*)d_in[4];
    const int*   out_idx= (const int*)d_in[5];
    float* out   = (float*)d_out;
    float* stats = (float*)d_ws;

    int n4 = out_size / 4;                 // 4.8M float4
    int zb = (n4 + 255) / 256;

    zero_kernel<<<zb, 256, 0, stream>>>((float4*)out, n4, stats);
    conv_kernel<<<KOFF * BLOCKS_PER_K, 256, 0, stream>>>(feats, weight, in_idx, out_idx, out);
    stats_kernel<<<1024, 256, 0, stream>>>(out, stats);
    norm_kernel<<<zb, 256, 0, stream>>>((float4*)out, n4, stats, gamma, beta);
}